// Round 9
// baseline (801.202 us; speedup 1.0000x reference)
//
#include <hip/hip_runtime.h>
#include <hip/hip_bf16.h>

#define N_NODES 100000
#define R_REL   8
#define E_EDGES 800000
#define D_FEAT  128
#define B_BASES 4
#define RN      (R_REL * N_NODES)
#define RE      (R_REL * E_EDGES)          // 6.4M edges

// radix partition: 784 coarse buckets of 128 dst nodes each
#define NBKT    784
#define BKT_CAP 9216                       // mean 8163, +11 sigma slack
#define P1_TPB  256
#define P1_EPT  32
#define P1_CHUNK (P1_TPB * P1_EPT)         // 8192 edges / WG
#define P1_NWG  ((RE + P1_CHUNK - 1) / P1_CHUNK)   // 782

typedef __attribute__((ext_vector_type(8))) short short8;
typedef __attribute__((ext_vector_type(4))) float floatx4;

__global__ __launch_bounds__(1024) void init_cursor_kernel(int* __restrict__ gcursor) {
    int t = threadIdx.x;
    if (t < NBKT) gcursor[t] = t * BKT_CAP;
}

// x (fp32) -> xb (bf162 pairs)
__global__ __launch_bounds__(256) void xcvt_kernel(
    const float* __restrict__ x, uint* __restrict__ xb) {
    int i = blockIdx.x * 256 + threadIdx.x;          // over N*64 pairs
    if (i >= N_NODES * 64) return;
    float2 v = *(const float2*)(x + 2 * (size_t)i);
    __hip_bfloat162 h = __float22bfloat162_rn(v);
    xb[i] = *(uint*)&h;
}

// wT[n][k] = bf16( k<512 ? bases[k][n] : loop_weight[k-512][n] )
__global__ __launch_bounds__(256) void wcvt_kernel(
    const float* __restrict__ bases, const float* __restrict__ loopw,
    unsigned short* __restrict__ wT) {
    int idx = blockIdx.x * 256 + threadIdx.x;        // over 128*640
    if (idx >= 128 * 640) return;
    int n = idx / 640, k = idx % 640;
    float v = (k < 512) ? bases[(size_t)k * 128 + n] : loopw[(size_t)(k - 512) * 128 + n];
    __hip_bfloat16 h = __float2bfloat16(v);
    wT[idx] = *(unsigned short*)&h;
}

// wT2[l][n][k] = bf16(ngnn_w[l][k][n])
__global__ __launch_bounds__(256) void wcvt2_kernel(
    const float* __restrict__ ngnn_w, unsigned short* __restrict__ wT2) {
    int idx = blockIdx.x * 256 + threadIdx.x;        // over 2*128*128
    if (idx >= 2 * 128 * 128) return;
    int l = idx >> 14, rem = idx & 16383;
    int n = rem >> 7, k = rem & 127;
    float v = ngnn_w[(size_t)l * 16384 + (size_t)k * 128 + n];
    __hip_bfloat16 h = __float2bfloat16(v);
    wT2[idx] = *(unsigned short*)&h;
}

// ---- pass 1: partition edges into coarse dst-buckets ----------------------
// record = src(17b) | dst_low(7b)<<17 | r(3b)<<24
// No LDS reorder: 6.3 KB LDS -> 32 waves/CU; scattered 4 B stores land in
// 784 hot runs/WG whose lines L2-merge (theory: WRITE ~= payload).
__global__ __launch_bounds__(256) void p1_kernel(
    const int* __restrict__ src, const int* __restrict__ dst,
    int* __restrict__ gcursor, int* __restrict__ ebuf2) {
    __shared__ int hist[NBKT];             // counts, then global bases
    __shared__ int cnt2[NBKT];             // local claim cursors
    int t = threadIdx.x;
    for (int i = t; i < NBKT; i += 256) { hist[i] = 0; cnt2[i] = 0; }
    __syncthreads();

    int e0 = blockIdx.x * P1_CHUNK;
    // pass A: histogram (dst only, coalesced)
#pragma unroll
    for (int i = 0; i < P1_EPT; ++i) {
        int e = e0 + i * P1_TPB + t;
        if (e < RE) atomicAdd(&hist[dst[e] >> 7], 1);   // native ds_add
    }
    __syncthreads();
    // reserve per-bucket global regions; hist becomes base
    for (int i = t; i < NBKT; i += 256) {
        int hv = hist[i];
        hist[i] = (hv > 0) ? atomicAdd(&gcursor[i], hv) : 0;
    }
    __syncthreads();
    // pass B: re-read (L2-warm), claim slot, fire-and-forget store
#pragma unroll
    for (int i = 0; i < P1_EPT; ++i) {
        int e = e0 + i * P1_TPB + t;
        if (e < RE) {
            int d = dst[e];
            int s = src[e];
            int r = e / E_EDGES;           // magic-mul division
            int b = d >> 7;
            int idx = atomicAdd(&cnt2[b], 1);          // ds_add_rtn
            int p = hist[b] + idx;
            if (p < (b + 1) * BKT_CAP)
                ebuf2[p] = s | ((d & 127) << 17) | (r << 24);
        }
    }
}

// ---- fused sort+gather: per bucket, LDS sort -> per-node aggregate -> y ---
// 1024 thr (16 waves), 2 WGs/CU (80 KB LDS). Wave w owns nodes [w*8, w*8+8).
template <bool XB>
__global__ __launch_bounds__(1024, 8) void agg2_kernel(
    const float* __restrict__ x,
    const uint*  __restrict__ xb,          // [N][64] bf162 pairs
    const int*   __restrict__ gcursor,
    const int*   __restrict__ ebuf2,
    const float* __restrict__ w_comp,
    __hip_bfloat162* __restrict__ y) {     // [N][256] bf162
    __shared__ int raw[BKT_CAP];           // 36 KB
    __shared__ int sorted[BKT_CAP];        // 36 KB (first 1 KB doubles as scan aux)
    __shared__ int cursors[1024];          // 4 KB
    __shared__ int segbeg[1024];           // 4 KB
    const int t = threadIdx.x;
    const int bucket = blockIdx.x;

    int cnt = gcursor[bucket] - bucket * BKT_CAP;
    if (cnt > BKT_CAP) cnt = BKT_CAP;
    const int* brec = ebuf2 + (size_t)bucket * BKT_CAP;
    for (int i = t; i < cnt; i += 1024) raw[i] = brec[i];
    cursors[t] = 0;
    __syncthreads();

    // degree histogram over keys (dn*8 + r)
    for (int i = t; i < cnt; i += 1024) {
        int rec = raw[i];
        int key = ((rec >> 17) & 127) * 8 + ((rec >> 24) & 7);
        atomicAdd(&cursors[key], 1);
    }
    __syncthreads();

    // exclusive scan of 1024 degrees (aux aliases sorted[0..1023])
    int deg = cursors[t];
    int* aux = sorted;
    aux[t] = deg;
    __syncthreads();
    int vv = deg;
    for (int off = 1; off < 1024; off <<= 1) {
        int yv = (t >= off) ? aux[t - off] : 0;
        __syncthreads();
        vv += yv;
        aux[t] = vv;
        __syncthreads();
    }
    int beg = vv - deg;
    cursors[t] = beg;
    segbeg[t]  = beg;
    __syncthreads();

    // in-LDS scatter to sorted order (src ids only)
    for (int i = t; i < cnt; i += 1024) {
        int rec = raw[i];
        int key = ((rec >> 17) & 127) * 8 + ((rec >> 24) & 7);
        int pos = atomicAdd(&cursors[key], 1);   // ds_add_rtn_u32
        sorted[pos] = rec & 0x1FFFF;
    }
    __syncthreads();

    // gather: wave owns 8 nodes; per (node,r) segment sum then basis fold
    const int wid = t >> 6, lane = t & 63;
    const float* xp  = x + 2 * lane;
    const uint*  xbp = xb + lane;
    for (int nn = 0; nn < 8; ++nn) {
        int nl = wid * 8 + nn;
        int node = bucket * 128 + nl;
        int key0 = nl * 8;
        float2 acc[B_BASES];
#pragma unroll
        for (int b = 0; b < B_BASES; ++b) acc[b] = make_float2(0.f, 0.f);
#pragma unroll
        for (int r = 0; r < R_REL; ++r) {
            int b0 = segbeg[key0 + r];
            int e0 = cursors[key0 + r];      // post-scatter == segment end
            int d = e0 - b0;
            float inv = 1.0f / (float)(d > 1 ? d : 1);
            float ax = 0.f, ay = 0.f;
            int i = b0;
            for (; i + 3 < e0; i += 4) {
                int s0 = sorted[i], s1 = sorted[i + 1], s2 = sorted[i + 2], s3 = sorted[i + 3];
                if (XB) {
                    uint u0 = xbp[(size_t)s0 * 64];
                    uint u1 = xbp[(size_t)s1 * 64];
                    uint u2 = xbp[(size_t)s2 * 64];
                    uint u3 = xbp[(size_t)s3 * 64];
                    ax += (__uint_as_float(u0 << 16) + __uint_as_float(u1 << 16))
                        + (__uint_as_float(u2 << 16) + __uint_as_float(u3 << 16));
                    ay += (__uint_as_float(u0 & 0xFFFF0000u) + __uint_as_float(u1 & 0xFFFF0000u))
                        + (__uint_as_float(u2 & 0xFFFF0000u) + __uint_as_float(u3 & 0xFFFF0000u));
                } else {
                    float2 a = *(const float2*)(xp + (size_t)s0 * D_FEAT);
                    float2 b = *(const float2*)(xp + (size_t)s1 * D_FEAT);
                    float2 cc = *(const float2*)(xp + (size_t)s2 * D_FEAT);
                    float2 d2 = *(const float2*)(xp + (size_t)s3 * D_FEAT);
                    ax += (a.x + b.x) + (cc.x + d2.x);
                    ay += (a.y + b.y) + (cc.y + d2.y);
                }
            }
            for (; i < e0; ++i) {
                int s = sorted[i];
                if (XB) {
                    uint u = xbp[(size_t)s * 64];
                    ax += __uint_as_float(u << 16);
                    ay += __uint_as_float(u & 0xFFFF0000u);
                } else {
                    float2 a = *(const float2*)(xp + (size_t)s * D_FEAT);
                    ax += a.x; ay += a.y;
                }
            }
#pragma unroll
            for (int b = 0; b < B_BASES; ++b) {
                float coef = w_comp[r * B_BASES + b] * inv;
                acc[b].x = fmaf(coef, ax, acc[b].x);
                acc[b].y = fmaf(coef, ay, acc[b].y);
            }
        }
        if (node < N_NODES) {
#pragma unroll
            for (int b = 0; b < B_BASES; ++b)
                y[(size_t)node * 256 + b * 64 + lane] = __float22bfloat162_rn(acc[b]);
        }
    }
}

// ---- MFMA GEMM: hb1 = bf16(relu([y | bf16(x)] @ wT^T + bias)), K=640 ------
__global__ __launch_bounds__(256) void gemm_big_mfma(
    const short* __restrict__ y,           // [N][512] bf16
    const float* __restrict__ x,           // [N][128] fp32
    const unsigned short* __restrict__ wT, // [128][640] bf16
    const float* __restrict__ bias,
    unsigned short* __restrict__ hb1) {    // [N][128] bf16
    const int wave = threadIdx.x >> 6;
    const int lane = threadIdx.x & 63;
    const int quad = lane >> 4;
    const int l16  = lane & 15;
    const int row0 = blockIdx.x * 64 + wave * 16;
    int arow = row0 + l16;
    if (arow >= N_NODES) arow = N_NODES - 1;

    floatx4 acc[8];
#pragma unroll
    for (int nt = 0; nt < 8; ++nt) acc[nt] = (floatx4){0.f, 0.f, 0.f, 0.f};

    const short* yrow = y + (size_t)arow * 512;
    const float* xrow = x + (size_t)arow * 128;
    const int koff = quad * 8;

    for (int ks = 0; ks < 16; ++ks) {
        int k0 = ks * 32 + koff;
        short8 a = *(const short8*)(yrow + k0);
#pragma unroll
        for (int nt = 0; nt < 8; ++nt) {
            int n = nt * 16 + l16;
            short8 b = *(const short8*)((const short*)wT + (size_t)n * 640 + k0);
            acc[nt] = __builtin_amdgcn_mfma_f32_16x16x32_bf16(a, b, acc[nt], 0, 0, 0);
        }
    }
#pragma unroll
    for (int ks = 0; ks < 4; ++ks) {
        int k0 = ks * 32 + koff;
        float4 fa = *(const float4*)(xrow + k0);
        float4 fb = *(const float4*)(xrow + k0 + 4);
        union { short8 s; uint u[4]; } ua;
        __hip_bfloat162 h0 = __float22bfloat162_rn(make_float2(fa.x, fa.y));
        __hip_bfloat162 h1 = __float22bfloat162_rn(make_float2(fa.z, fa.w));
        __hip_bfloat162 h2 = __float22bfloat162_rn(make_float2(fb.x, fb.y));
        __hip_bfloat162 h3 = __float22bfloat162_rn(make_float2(fb.z, fb.w));
        ua.u[0] = *(uint*)&h0; ua.u[1] = *(uint*)&h1;
        ua.u[2] = *(uint*)&h2; ua.u[3] = *(uint*)&h3;
#pragma unroll
        for (int nt = 0; nt < 8; ++nt) {
            int n = nt * 16 + l16;
            short8 b = *(const short8*)((const short*)wT + (size_t)n * 640 + 512 + k0);
            acc[nt] = __builtin_amdgcn_mfma_f32_16x16x32_bf16(ua.s, b, acc[nt], 0, 0, 0);
        }
    }

#pragma unroll
    for (int nt = 0; nt < 8; ++nt) {
        int n = nt * 16 + l16;
        float bs = bias[n];
#pragma unroll
        for (int i = 0; i < 4; ++i) {
            int m = row0 + quad * 4 + i;
            if (m < N_NODES) {
                float v = fmaxf(acc[nt][i] + bs, 0.f);
                __hip_bfloat16 h = __float2bfloat16(v);
                hb1[(size_t)m * D_FEAT + n] = *(unsigned short*)&h;
            }
        }
    }
}

// ---- NGNN MFMA layer: C = relu(A @ wTl^T), A bf16 [N][128] ---------------
template <bool OUT_BF16>
__global__ __launch_bounds__(256) void ngnn_mfma(
    const short* __restrict__ A,             // [N][128] bf16
    const unsigned short* __restrict__ wTl,  // [128][128] bf16, n-major
    void* __restrict__ C) {
    const int wave = threadIdx.x >> 6;
    const int lane = threadIdx.x & 63;
    const int quad = lane >> 4;
    const int l16  = lane & 15;
    const int row0 = blockIdx.x * 64 + wave * 16;
    int arow = row0 + l16;
    if (arow >= N_NODES) arow = N_NODES - 1;

    floatx4 acc[8];
#pragma unroll
    for (int nt = 0; nt < 8; ++nt) acc[nt] = (floatx4){0.f, 0.f, 0.f, 0.f};

    const short* ar = A + (size_t)arow * 128;
    const int koff = quad * 8;
#pragma unroll
    for (int ks = 0; ks < 4; ++ks) {
        int k0 = ks * 32 + koff;
        short8 a = *(const short8*)(ar + k0);
#pragma unroll
        for (int nt = 0; nt < 8; ++nt) {
            int n = nt * 16 + l16;
            short8 b = *(const short8*)((const short*)wTl + (size_t)n * 128 + k0);
            acc[nt] = __builtin_amdgcn_mfma_f32_16x16x32_bf16(a, b, acc[nt], 0, 0, 0);
        }
    }

#pragma unroll
    for (int nt = 0; nt < 8; ++nt) {
        int n = nt * 16 + l16;
#pragma unroll
        for (int i = 0; i < 4; ++i) {
            int m = row0 + quad * 4 + i;
            if (m < N_NODES) {
                float v = fmaxf(acc[nt][i], 0.f);
                if (OUT_BF16) {
                    __hip_bfloat16 h = __float2bfloat16(v);
                    ((unsigned short*)C)[(size_t)m * D_FEAT + n] = *(unsigned short*)&h;
                } else {
                    ((float*)C)[(size_t)m * D_FEAT + n] = v;
                }
            }
        }
    }
}

extern "C" void kernel_launch(void* const* d_in, const int* in_sizes, int n_in,
                              void* d_out, int out_size, void* d_ws, size_t ws_size,
                              hipStream_t stream) {
    const float* x           = (const float*)d_in[0];
    const int*   edge_src    = (const int*)d_in[1];
    const int*   edge_dst    = (const int*)d_in[2];
    const float* w_comp      = (const float*)d_in[3];
    const float* bases       = (const float*)d_in[4];
    const float* loop_weight = (const float*)d_in[5];
    const float* h_bias      = (const float*)d_in[6];
    const float* ngnn_w      = (const float*)d_in[7];
    float* out = (float*)d_out;

    // workspace layout (~131.6 MB base; +25.6 MB optional xb)
    char* ws = (char*)d_ws;
    size_t off = 0;
    __hip_bfloat162* y = (__hip_bfloat162*)(ws + off);
    off += (size_t)N_NODES * 512 * 2;              // 102.4 MB
    int* ebuf2 = (int*)(ws + off);                 // 784*9216*4 = 28.9 MB
    unsigned short* hb1 = (unsigned short*)(ws + off);  // overlays ebuf2 (dead post-agg2)
    off += (size_t)NBKT * BKT_CAP * 4;
    int* gcursor = (int*)(ws + off);
    off += 4096;
    unsigned short* wT = (unsigned short*)(ws + off);
    off += (size_t)128 * 640 * 2;                  // 160 KB
    unsigned short* wT2 = (unsigned short*)(ws + off);
    off += (size_t)2 * 128 * 128 * 2;              // 64 KB
    uint* xb = (uint*)(ws + off);
    size_t xb_bytes = (size_t)N_NODES * 64 * 4;    // 25.6 MB
    const bool use_bf16_x = (ws_size >= off + xb_bytes);   // ws_size constant across calls
    // hb2: overlays xb (dead post-agg2) when present, else the y region (dead post-gemm_big)
    unsigned short* hb2 = use_bf16_x ? (unsigned short*)xb : (unsigned short*)y;

    const int GEMM_GRID = (N_NODES + 63) / 64;     // 1563

    // 0) weight/x conversions
    wcvt_kernel<<<(128 * 640 + 255) / 256, 256, 0, stream>>>(bases, loop_weight, wT);
    wcvt2_kernel<<<(2 * 128 * 128 + 255) / 256, 256, 0, stream>>>(ngnn_w, wT2);
    if (use_bf16_x)
        xcvt_kernel<<<(N_NODES * 64 + 255) / 256, 256, 0, stream>>>(x, xb);

    // 1) bucket partition (occupancy-first, L2-merged scattered writes)
    init_cursor_kernel<<<1, 1024, 0, stream>>>(gcursor);
    p1_kernel<<<P1_NWG, P1_TPB, 0, stream>>>(edge_src, edge_dst, gcursor, ebuf2);

    // 2) fused LDS-sort + gather -> y (bf16, basis-combined, deg-normalized)
    if (use_bf16_x)
        agg2_kernel<true><<<NBKT, 1024, 0, stream>>>(x, xb, gcursor, ebuf2, w_comp, y);
    else
        agg2_kernel<false><<<NBKT, 1024, 0, stream>>>(x, nullptr, gcursor, ebuf2, w_comp, y);

    // 3) hb1 = bf16(relu([y|x] @ [bases;loop_w] + bias))  -- MFMA
    gemm_big_mfma<<<GEMM_GRID, 256, 0, stream>>>(
        (const short*)y, x, wT, h_bias, hb1);

    // 4) NGNN: hb2 = bf16(relu(hb1 @ w0));  out = relu(hb2 @ w1)  -- MFMA
    ngnn_mfma<true><<<GEMM_GRID, 256, 0, stream>>>(
        (const short*)hb1, wT2, (void*)hb2);
    ngnn_mfma<false><<<GEMM_GRID, 256, 0, stream>>>(
        (const short*)hb2, wT2 + 128 * 128, (void*)out);
}

// Round 10
// 727.422 us; speedup vs baseline: 1.1014x; 1.1014x over previous
//
#include <hip/hip_runtime.h>
#include <hip/hip_bf16.h>

#define N_NODES 100000
#define R_REL   8
#define E_EDGES 800000
#define D_FEAT  128
#define B_BASES 4
#define RN      (R_REL * N_NODES)
#define RE      (R_REL * E_EDGES)          // 6.4M edges

// radix partition: 784 coarse buckets of 128 dst nodes each
#define NBKT    784
#define BKT_CAP 9216                       // mean 8163, +11 sigma slack
#define P1_TPB  256
#define P1_EPT  16
#define P1_CHUNK (P1_TPB * P1_EPT)         // 4096 edges / WG
#define P1_NWG  ((RE + P1_CHUNK - 1) / P1_CHUNK)   // 1563

typedef __attribute__((ext_vector_type(8))) short short8;
typedef __attribute__((ext_vector_type(4))) float floatx4;

__global__ __launch_bounds__(1024) void init_cursor_kernel(int* __restrict__ gcursor) {
    int t = threadIdx.x;
    if (t < NBKT) gcursor[t] = t * BKT_CAP;
}

// x (fp32) -> xb (bf162 pairs)
__global__ __launch_bounds__(256) void xcvt_kernel(
    const float* __restrict__ x, uint* __restrict__ xb) {
    int i = blockIdx.x * 256 + threadIdx.x;          // over N*64 pairs
    if (i >= N_NODES * 64) return;
    float2 v = *(const float2*)(x + 2 * (size_t)i);
    __hip_bfloat162 h = __float22bfloat162_rn(v);
    xb[i] = *(uint*)&h;
}

// wT[n][k] = bf16( k<512 ? bases[k][n] : loop_weight[k-512][n] )
__global__ __launch_bounds__(256) void wcvt_kernel(
    const float* __restrict__ bases, const float* __restrict__ loopw,
    unsigned short* __restrict__ wT) {
    int idx = blockIdx.x * 256 + threadIdx.x;        // over 128*640
    if (idx >= 128 * 640) return;
    int n = idx / 640, k = idx % 640;
    float v = (k < 512) ? bases[(size_t)k * 128 + n] : loopw[(size_t)(k - 512) * 128 + n];
    __hip_bfloat16 h = __float2bfloat16(v);
    wT[idx] = *(unsigned short*)&h;
}

// wT2[l][n][k] = bf16(ngnn_w[l][k][n])
__global__ __launch_bounds__(256) void wcvt2_kernel(
    const float* __restrict__ ngnn_w, unsigned short* __restrict__ wT2) {
    int idx = blockIdx.x * 256 + threadIdx.x;        // over 2*128*128
    if (idx >= 2 * 128 * 128) return;
    int l = idx >> 14, rem = idx & 16383;
    int n = rem >> 7, k = rem & 127;
    float v = ngnn_w[(size_t)l * 16384 + (size_t)k * 128 + n];
    __hip_bfloat16 h = __float2bfloat16(v);
    wT2[idx] = *(unsigned short*)&h;
}

// ---- pass 1: partition edges into coarse dst-buckets ----------------------
// record = src(17b) | dst_low(7b)<<17 | r(3b)<<24
// R8-style LDS reorder (coalesced global writeout) but 26.4 KB LDS ->
// 6 WGs/CU (24 waves): histogram-only pass A (no reg arrays), re-read in
// reorder (L2-warm), binary-search writeout (no bb array).
__global__ __launch_bounds__(256) void p1_kernel(
    const int* __restrict__ src, const int* __restrict__ dst,
    int* __restrict__ gcursor, int* __restrict__ ebuf2) {
    __shared__ int hist[NBKT];             // counts, then global bases
    __shared__ int cnt2[NBKT];             // local claim cursors
    __shared__ int lofs[NBKT];             // local exclusive offsets
    __shared__ int aux[256];
    __shared__ int recs[P1_CHUNK];         // 16 KB
    int t = threadIdx.x;
    for (int i = t; i < NBKT; i += 256) { hist[i] = 0; cnt2[i] = 0; }
    __syncthreads();

    int e0 = blockIdx.x * P1_CHUNK;
    // pass A: histogram (dst only, coalesced)
#pragma unroll
    for (int i = 0; i < P1_EPT; ++i) {
        int e = e0 + i * P1_TPB + t;
        if (e < RE) atomicAdd(&hist[dst[e] >> 7], 1);   // native ds_add
    }
    __syncthreads();

    // exclusive scan of hist[784] -> lofs: 4 consecutive per thread + HS scan
    int k0 = t * 4;
    int c0 = (k0 + 0 < NBKT) ? hist[k0 + 0] : 0;
    int c1 = (k0 + 1 < NBKT) ? hist[k0 + 1] : 0;
    int c2 = (k0 + 2 < NBKT) ? hist[k0 + 2] : 0;
    int c3 = (k0 + 3 < NBKT) ? hist[k0 + 3] : 0;
    int s1 = c0 + c1, s2 = s1 + c2, s3 = s2 + c3;
    aux[t] = s3;
    __syncthreads();
    int vv = s3;
    for (int off = 1; off < 256; off <<= 1) {
        int yv = (t >= off) ? aux[t - off] : 0;
        __syncthreads();
        vv += yv;
        aux[t] = vv;
        __syncthreads();
    }
    int total = aux[255];
    int texcl = vv - s3;
    if (k0 + 0 < NBKT) lofs[k0 + 0] = texcl;
    if (k0 + 1 < NBKT) lofs[k0 + 1] = texcl + c0;
    if (k0 + 2 < NBKT) lofs[k0 + 2] = texcl + s1;
    if (k0 + 3 < NBKT) lofs[k0 + 3] = texcl + s2;
    __syncthreads();
    // reserve per-bucket global regions; hist becomes base
    for (int i = t; i < NBKT; i += 256) {
        int hv = hist[i];
        hist[i] = (hv > 0) ? atomicAdd(&gcursor[i], hv) : 0;
    }
    __syncthreads();

    // reorder: re-read edges (L2-warm), claim LDS slot, write rec to LDS
#pragma unroll
    for (int i = 0; i < P1_EPT; ++i) {
        int e = e0 + i * P1_TPB + t;
        if (e < RE) {
            int d = dst[e];
            int s = src[e];
            int r = e / E_EDGES;           // magic-mul division
            int b = d >> 7;
            int pos = lofs[b] + atomicAdd(&cnt2[b], 1);   // ds_add_rtn
            recs[pos] = s | ((d & 127) << 17) | (r << 24);
        }
    }
    __syncthreads();

    // coalesced writeout; bucket of index i via binary search over lofs
    for (int i = t; i < total; i += 256) {
        int lo = 0, hi = NBKT;
        while (hi - lo > 1) {              // 10 iters: largest b with lofs[b] <= i
            int mid = (lo + hi) >> 1;
            if (lofs[mid] <= i) lo = mid; else hi = mid;
        }
        int p = hist[lo] + (i - lofs[lo]);
        if (p < (lo + 1) * BKT_CAP) ebuf2[p] = recs[i];
    }
}

// ---- fused sort+gather: per bucket, LDS sort -> per-node aggregate -> y ---
// 1024 thr (16 waves), 2 WGs/CU (80 KB LDS). Wave w owns nodes [w*8, w*8+8).
template <bool XB>
__global__ __launch_bounds__(1024, 8) void agg2_kernel(
    const float* __restrict__ x,
    const uint*  __restrict__ xb,          // [N][64] bf162 pairs
    const int*   __restrict__ gcursor,
    const int*   __restrict__ ebuf2,
    const float* __restrict__ w_comp,
    __hip_bfloat162* __restrict__ y) {     // [N][256] bf162
    __shared__ int raw[BKT_CAP];           // 36 KB
    __shared__ int sorted[BKT_CAP];        // 36 KB (first 1 KB doubles as scan aux)
    __shared__ int cursors[1024];          // 4 KB
    __shared__ int segbeg[1024];           // 4 KB
    const int t = threadIdx.x;
    const int bucket = blockIdx.x;

    int cnt = gcursor[bucket] - bucket * BKT_CAP;
    if (cnt > BKT_CAP) cnt = BKT_CAP;
    const int* brec = ebuf2 + (size_t)bucket * BKT_CAP;
    for (int i = t; i < cnt; i += 1024) raw[i] = brec[i];
    cursors[t] = 0;
    __syncthreads();

    // degree histogram over keys (dn*8 + r)
    for (int i = t; i < cnt; i += 1024) {
        int rec = raw[i];
        int key = ((rec >> 17) & 127) * 8 + ((rec >> 24) & 7);
        atomicAdd(&cursors[key], 1);
    }
    __syncthreads();

    // exclusive scan of 1024 degrees (aux aliases sorted[0..1023])
    int deg = cursors[t];
    int* aux = sorted;
    aux[t] = deg;
    __syncthreads();
    int vv = deg;
    for (int off = 1; off < 1024; off <<= 1) {
        int yv = (t >= off) ? aux[t - off] : 0;
        __syncthreads();
        vv += yv;
        aux[t] = vv;
        __syncthreads();
    }
    int beg = vv - deg;
    cursors[t] = beg;
    segbeg[t]  = beg;
    __syncthreads();

    // in-LDS scatter to sorted order (src ids only)
    for (int i = t; i < cnt; i += 1024) {
        int rec = raw[i];
        int key = ((rec >> 17) & 127) * 8 + ((rec >> 24) & 7);
        int pos = atomicAdd(&cursors[key], 1);   // ds_add_rtn_u32
        sorted[pos] = rec & 0x1FFFF;
    }
    __syncthreads();

    // gather: wave owns 8 nodes; per (node,r) segment sum then basis fold
    const int wid = t >> 6, lane = t & 63;
    const float* xp  = x + 2 * lane;
    const uint*  xbp = xb + lane;
    for (int nn = 0; nn < 8; ++nn) {
        int nl = wid * 8 + nn;
        int node = bucket * 128 + nl;
        int key0 = nl * 8;
        float2 acc[B_BASES];
#pragma unroll
        for (int b = 0; b < B_BASES; ++b) acc[b] = make_float2(0.f, 0.f);
#pragma unroll
        for (int r = 0; r < R_REL; ++r) {
            int b0 = segbeg[key0 + r];
            int e0 = cursors[key0 + r];      // post-scatter == segment end
            int d = e0 - b0;
            float inv = 1.0f / (float)(d > 1 ? d : 1);
            float ax = 0.f, ay = 0.f;
            int i = b0;
            for (; i + 3 < e0; i += 4) {
                int s0 = sorted[i], s1 = sorted[i + 1], s2 = sorted[i + 2], s3 = sorted[i + 3];
                if (XB) {
                    uint u0 = xbp[(size_t)s0 * 64];
                    uint u1 = xbp[(size_t)s1 * 64];
                    uint u2 = xbp[(size_t)s2 * 64];
                    uint u3 = xbp[(size_t)s3 * 64];
                    ax += (__uint_as_float(u0 << 16) + __uint_as_float(u1 << 16))
                        + (__uint_as_float(u2 << 16) + __uint_as_float(u3 << 16));
                    ay += (__uint_as_float(u0 & 0xFFFF0000u) + __uint_as_float(u1 & 0xFFFF0000u))
                        + (__uint_as_float(u2 & 0xFFFF0000u) + __uint_as_float(u3 & 0xFFFF0000u));
                } else {
                    float2 a = *(const float2*)(xp + (size_t)s0 * D_FEAT);
                    float2 b = *(const float2*)(xp + (size_t)s1 * D_FEAT);
                    float2 cc = *(const float2*)(xp + (size_t)s2 * D_FEAT);
                    float2 d2 = *(const float2*)(xp + (size_t)s3 * D_FEAT);
                    ax += (a.x + b.x) + (cc.x + d2.x);
                    ay += (a.y + b.y) + (cc.y + d2.y);
                }
            }
            for (; i < e0; ++i) {
                int s = sorted[i];
                if (XB) {
                    uint u = xbp[(size_t)s * 64];
                    ax += __uint_as_float(u << 16);
                    ay += __uint_as_float(u & 0xFFFF0000u);
                } else {
                    float2 a = *(const float2*)(xp + (size_t)s * D_FEAT);
                    ax += a.x; ay += a.y;
                }
            }
#pragma unroll
            for (int b = 0; b < B_BASES; ++b) {
                float coef = w_comp[r * B_BASES + b] * inv;
                acc[b].x = fmaf(coef, ax, acc[b].x);
                acc[b].y = fmaf(coef, ay, acc[b].y);
            }
        }
        if (node < N_NODES) {
#pragma unroll
            for (int b = 0; b < B_BASES; ++b)
                y[(size_t)node * 256 + b * 64 + lane] = __float22bfloat162_rn(acc[b]);
        }
    }
}

// ---- MFMA GEMM: hb1 = bf16(relu([y | x] @ wT^T + bias)), K=640 ------------
// XB: phase-2 A comes from pre-converted xb (bf16); else fp32 x + in-reg cvt
template <bool XB>
__global__ __launch_bounds__(256) void gemm_big_mfma(
    const short* __restrict__ y,           // [N][512] bf16
    const float* __restrict__ x,           // [N][128] fp32
    const short* __restrict__ xbs,         // [N][128] bf16 (when XB)
    const unsigned short* __restrict__ wT, // [128][640] bf16
    const float* __restrict__ bias,
    unsigned short* __restrict__ hb1) {    // [N][128] bf16
    const int wave = threadIdx.x >> 6;
    const int lane = threadIdx.x & 63;
    const int quad = lane >> 4;
    const int l16  = lane & 15;
    const int row0 = blockIdx.x * 64 + wave * 16;
    int arow = row0 + l16;
    if (arow >= N_NODES) arow = N_NODES - 1;

    floatx4 acc[8];
#pragma unroll
    for (int nt = 0; nt < 8; ++nt) acc[nt] = (floatx4){0.f, 0.f, 0.f, 0.f};

    const short* yrow = y + (size_t)arow * 512;
    const int koff = quad * 8;

    for (int ks = 0; ks < 16; ++ks) {
        int k0 = ks * 32 + koff;
        short8 a = *(const short8*)(yrow + k0);
#pragma unroll
        for (int nt = 0; nt < 8; ++nt) {
            int n = nt * 16 + l16;
            short8 b = *(const short8*)((const short*)wT + (size_t)n * 640 + k0);
            acc[nt] = __builtin_amdgcn_mfma_f32_16x16x32_bf16(a, b, acc[nt], 0, 0, 0);
        }
    }
#pragma unroll
    for (int ks = 0; ks < 4; ++ks) {
        int k0 = ks * 32 + koff;
        short8 a2;
        if (XB) {
            a2 = *(const short8*)(xbs + (size_t)arow * 128 + k0);
        } else {
            const float* xrow = x + (size_t)arow * 128;
            float4 fa = *(const float4*)(xrow + k0);
            float4 fb = *(const float4*)(xrow + k0 + 4);
            union { short8 s; uint u[4]; } ua;
            __hip_bfloat162 h0 = __float22bfloat162_rn(make_float2(fa.x, fa.y));
            __hip_bfloat162 h1 = __float22bfloat162_rn(make_float2(fa.z, fa.w));
            __hip_bfloat162 h2 = __float22bfloat162_rn(make_float2(fb.x, fb.y));
            __hip_bfloat162 h3 = __float22bfloat162_rn(make_float2(fb.z, fb.w));
            ua.u[0] = *(uint*)&h0; ua.u[1] = *(uint*)&h1;
            ua.u[2] = *(uint*)&h2; ua.u[3] = *(uint*)&h3;
            a2 = ua.s;
        }
#pragma unroll
        for (int nt = 0; nt < 8; ++nt) {
            int n = nt * 16 + l16;
            short8 b = *(const short8*)((const short*)wT + (size_t)n * 640 + 512 + k0);
            acc[nt] = __builtin_amdgcn_mfma_f32_16x16x32_bf16(a2, b, acc[nt], 0, 0, 0);
        }
    }

#pragma unroll
    for (int nt = 0; nt < 8; ++nt) {
        int n = nt * 16 + l16;
        float bs = bias[n];
#pragma unroll
        for (int i = 0; i < 4; ++i) {
            int m = row0 + quad * 4 + i;
            if (m < N_NODES) {
                float v = fmaxf(acc[nt][i] + bs, 0.f);
                __hip_bfloat16 h = __float2bfloat16(v);
                hb1[(size_t)m * D_FEAT + n] = *(unsigned short*)&h;
            }
        }
    }
}

// ---- NGNN MFMA layer: C = relu(A @ wTl^T), A bf16 [N][128] ---------------
template <bool OUT_BF16>
__global__ __launch_bounds__(256) void ngnn_mfma(
    const short* __restrict__ A,             // [N][128] bf16
    const unsigned short* __restrict__ wTl,  // [128][128] bf16, n-major
    void* __restrict__ C) {
    const int wave = threadIdx.x >> 6;
    const int lane = threadIdx.x & 63;
    const int quad = lane >> 4;
    const int l16  = lane & 15;
    const int row0 = blockIdx.x * 64 + wave * 16;
    int arow = row0 + l16;
    if (arow >= N_NODES) arow = N_NODES - 1;

    floatx4 acc[8];
#pragma unroll
    for (int nt = 0; nt < 8; ++nt) acc[nt] = (floatx4){0.f, 0.f, 0.f, 0.f};

    const short* ar = A + (size_t)arow * 128;
    const int koff = quad * 8;
#pragma unroll
    for (int ks = 0; ks < 4; ++ks) {
        int k0 = ks * 32 + koff;
        short8 a = *(const short8*)(ar + k0);
#pragma unroll
        for (int nt = 0; nt < 8; ++nt) {
            int n = nt * 16 + l16;
            short8 b = *(const short8*)((const short*)wTl + (size_t)n * 128 + k0);
            acc[nt] = __builtin_amdgcn_mfma_f32_16x16x32_bf16(a, b, acc[nt], 0, 0, 0);
        }
    }

#pragma unroll
    for (int nt = 0; nt < 8; ++nt) {
        int n = nt * 16 + l16;
#pragma unroll
        for (int i = 0; i < 4; ++i) {
            int m = row0 + quad * 4 + i;
            if (m < N_NODES) {
                float v = fmaxf(acc[nt][i], 0.f);
                if (OUT_BF16) {
                    __hip_bfloat16 h = __float2bfloat16(v);
                    ((unsigned short*)C)[(size_t)m * D_FEAT + n] = *(unsigned short*)&h;
                } else {
                    ((float*)C)[(size_t)m * D_FEAT + n] = v;
                }
            }
        }
    }
}

extern "C" void kernel_launch(void* const* d_in, const int* in_sizes, int n_in,
                              void* d_out, int out_size, void* d_ws, size_t ws_size,
                              hipStream_t stream) {
    const float* x           = (const float*)d_in[0];
    const int*   edge_src    = (const int*)d_in[1];
    const int*   edge_dst    = (const int*)d_in[2];
    const float* w_comp      = (const float*)d_in[3];
    const float* bases       = (const float*)d_in[4];
    const float* loop_weight = (const float*)d_in[5];
    const float* h_bias      = (const float*)d_in[6];
    const float* ngnn_w      = (const float*)d_in[7];
    float* out = (float*)d_out;

    // workspace layout (~131.6 MB base; +25.6 MB optional xb)
    char* ws = (char*)d_ws;
    size_t off = 0;
    __hip_bfloat162* y = (__hip_bfloat162*)(ws + off);
    off += (size_t)N_NODES * 512 * 2;              // 102.4 MB
    int* ebuf2 = (int*)(ws + off);                 // 784*9216*4 = 28.9 MB
    unsigned short* hb1 = (unsigned short*)(ws + off);  // overlays ebuf2 (dead post-agg2)
    off += (size_t)NBKT * BKT_CAP * 4;
    int* gcursor = (int*)(ws + off);
    off += 4096;
    unsigned short* wT = (unsigned short*)(ws + off);
    off += (size_t)128 * 640 * 2;                  // 160 KB
    unsigned short* wT2 = (unsigned short*)(ws + off);
    off += (size_t)2 * 128 * 128 * 2;              // 64 KB
    uint* xb = (uint*)(ws + off);
    size_t xb_bytes = (size_t)N_NODES * 64 * 4;    // 25.6 MB
    const bool use_bf16_x = (ws_size >= off + xb_bytes);   // ws_size constant across calls
    // hb2: overlays xb (xb dead after gemm_big) or y region (dead post-gemm_big)
    unsigned short* hb2 = use_bf16_x ? (unsigned short*)xb : (unsigned short*)y;

    const int GEMM_GRID = (N_NODES + 63) / 64;     // 1563

    // 0) weight/x conversions
    wcvt_kernel<<<(128 * 640 + 255) / 256, 256, 0, stream>>>(bases, loop_weight, wT);
    wcvt2_kernel<<<(2 * 128 * 128 + 255) / 256, 256, 0, stream>>>(ngnn_w, wT2);
    if (use_bf16_x)
        xcvt_kernel<<<(N_NODES * 64 + 255) / 256, 256, 0, stream>>>(x, xb);

    // 1) bucket partition (R8 coalesced writeout, 3x occupancy)
    init_cursor_kernel<<<1, 1024, 0, stream>>>(gcursor);
    p1_kernel<<<P1_NWG, P1_TPB, 0, stream>>>(edge_src, edge_dst, gcursor, ebuf2);

    // 2) fused LDS-sort + gather -> y (bf16, basis-combined, deg-normalized)
    if (use_bf16_x)
        agg2_kernel<true><<<NBKT, 1024, 0, stream>>>(x, xb, gcursor, ebuf2, w_comp, y);
    else
        agg2_kernel<false><<<NBKT, 1024, 0, stream>>>(x, nullptr, gcursor, ebuf2, w_comp, y);

    // 3) hb1 = bf16(relu([y|x] @ [bases;loop_w] + bias))  -- MFMA
    if (use_bf16_x)
        gemm_big_mfma<true><<<GEMM_GRID, 256, 0, stream>>>(
            (const short*)y, x, (const short*)xb, wT, h_bias, hb1);
    else
        gemm_big_mfma<false><<<GEMM_GRID, 256, 0, stream>>>(
            (const short*)y, x, nullptr, wT, h_bias, hb1);

    // 4) NGNN: hb2 = bf16(relu(hb1 @ w0));  out = relu(hb2 @ w1)  -- MFMA
    ngnn_mfma<true><<<GEMM_GRID, 256, 0, stream>>>(
        (const short*)hb1, wT2, (void*)hb2);
    ngnn_mfma<false><<<GEMM_GRID, 256, 0, stream>>>(
        (const short*)hb2, wT2 + 128 * 128, (void*)out);
}